// Round 1
// baseline (4084.295 us; speedup 1.0000x reference)
//
#include <hip/hip_runtime.h>
#include <math.h>

#define N_NODES  25000
#define N_EDGES  300000
#define N_GRAPHS 256
#define EMB_DIM  92
#define HID      256

__device__ __forceinline__ float softplusf(float x){
    // logaddexp(x, 0) == max(x,0) + log1p(exp(-|x|))  (matches jax.nn.softplus)
    return fmaxf(x, 0.0f) + log1pf(expf(-fabsf(x)));
}

// ---------------------------------------------------------------- embedding gather
__global__ void gather_emb_kernel(const int* __restrict__ atoms,
                                  const float* __restrict__ emb,
                                  float* __restrict__ x)
{
    const int n = blockIdx.x;
    const int c = threadIdx.x;
    if (c < EMB_DIM){
        const int a = atoms[n];
        x[(size_t)n*EMB_DIM + c] = emb[(size_t)a*EMB_DIM + c];
    }
}

// ---------------------------------------------------------------- layer-0 edge conv (C=92)
template<int EPB>
__global__ __launch_bounds__(128) void edge_conv92_kernel(
    const int* __restrict__ src, const int* __restrict__ dst,
    const float* __restrict__ ea,
    const float* __restrict__ w1, const float* __restrict__ b1,
    const float* __restrict__ w2, const float* __restrict__ b2,
    const float* __restrict__ x, float* __restrict__ agg)
{
    constexpr int C = EMB_DIM;
    __shared__ float h1[EPB][C];            // 16*92*4 = 5.9 KB
    const int e0  = blockIdx.x * EPB;
    const int tid = threadIdx.x;

    // phase 1: h1 = softplus(ea @ w1 + b1)
    for (int idx = tid; idx < EPB*C; idx += 128){
        const int e = idx / C, k = idx - e*C;
        const float4 a = *(const float4*)(ea + (size_t)(e0+e)*4);
        float v = fmaf(a.x, w1[k], fmaf(a.y, w1[C+k], fmaf(a.z, w1[2*C+k], fmaf(a.w, w1[3*C+k], b1[k]))));
        h1[e][k] = softplusf(v);
    }
    __syncthreads();

    // phase 2: ee = h1 @ w2 + b2, then msg = ee * x[src], scatter-add at dst
    const int c = tid;
    if (c < C){
        float acc[EPB];
        #pragma unroll
        for (int e=0;e<EPB;e++) acc[e] = 0.0f;
        for (int k=0;k<C;k+=4){             // 92 = 23*4
            const float w0  = w2[(k+0)*C+c];
            const float w1v = w2[(k+1)*C+c];
            const float w2v = w2[(k+2)*C+c];
            const float w3v = w2[(k+3)*C+c];
            #pragma unroll
            for (int e=0;e<EPB;e++){
                const float4 hv = *(const float4*)&h1[e][k];
                acc[e] = fmaf(hv.x,w0,fmaf(hv.y,w1v,fmaf(hv.z,w2v,fmaf(hv.w,w3v,acc[e]))));
            }
        }
        const float bb = b2[c];
        for (int e=0;e<EPB;e++){
            const int eid = e0 + e;
            const int s = src[eid], d = dst[eid];
            const float msg = (acc[e] + bb) * x[(size_t)s*C + c];
            atomicAdd(&agg[(size_t)d*C + c], msg);
        }
    }
}

// ---------------------------------------------------------------- layers 1-3 edge conv (C=256)
template<int EPB>
__global__ __launch_bounds__(256) void edge_conv256_kernel(
    const int* __restrict__ src, const int* __restrict__ dst,
    const float* __restrict__ ea,
    const float* __restrict__ w1, const float* __restrict__ b1,
    const float* __restrict__ w2, const float* __restrict__ b2,
    const float* __restrict__ x, float* __restrict__ agg)
{
    constexpr int C = HID;
    __shared__ float h1[EPB][C];            // 16 KB
    const int e0  = blockIdx.x * EPB;
    const int tid = threadIdx.x;

    // phase 1: thread k computes h1[e][k] for all EPB edges
    {
        const int k = tid;
        const float w10 = w1[k], w11 = w1[C+k], w12 = w1[2*C+k], w13 = w1[3*C+k];
        const float bk = b1[k];
        #pragma unroll
        for (int e=0;e<EPB;e++){
            const float4 a = *(const float4*)(ea + (size_t)(e0+e)*4);
            const float v = fmaf(a.x,w10,fmaf(a.y,w11,fmaf(a.z,w12,fmaf(a.w,w13,bk))));
            h1[e][k] = softplusf(v);
        }
    }
    __syncthreads();

    // phase 2: register-tiled GEMM  [16 e x 256 c] = h1[16 x 256] @ w2[256 x 256]
    // thread (eg, cg): 4 edges (4*eg..), 4 contiguous cols (4*cg..)
    const int cg = tid & 63;
    const int eg = tid >> 6;
    const int c0 = cg * 4;
    float acc[4][4];
    #pragma unroll
    for (int e=0;e<4;e++){
        #pragma unroll
        for (int c=0;c<4;c++) acc[e][c] = 0.0f;
    }
    for (int k=0;k<C;k+=4){
        float hvf[4][4];
        #pragma unroll
        for (int e=0;e<4;e++){
            const float4 t4 = *(const float4*)&h1[4*eg+e][k];  // wave-broadcast read
            hvf[e][0]=t4.x; hvf[e][1]=t4.y; hvf[e][2]=t4.z; hvf[e][3]=t4.w;
        }
        #pragma unroll
        for (int kk=0;kk<4;kk++){
            const float4 wv = *(const float4*)(w2 + (size_t)(k+kk)*C + c0); // coalesced 1KB/wave
            #pragma unroll
            for (int e=0;e<4;e++){
                acc[e][0] = fmaf(hvf[e][kk], wv.x, acc[e][0]);
                acc[e][1] = fmaf(hvf[e][kk], wv.y, acc[e][1]);
                acc[e][2] = fmaf(hvf[e][kk], wv.z, acc[e][2]);
                acc[e][3] = fmaf(hvf[e][kk], wv.w, acc[e][3]);
            }
        }
    }
    const float4 bb = *(const float4*)(b2 + c0);
    #pragma unroll
    for (int e=0;e<4;e++){
        const int eid = e0 + 4*eg + e;
        const int s = src[eid], d = dst[eid];
        const float4 xv = *(const float4*)(x + (size_t)s*C + c0);
        float* ap = agg + (size_t)d*C + c0;
        atomicAdd(ap+0, (acc[e][0]+bb.x)*xv.x);
        atomicAdd(ap+1, (acc[e][1]+bb.y)*xv.y);
        atomicAdd(ap+2, (acc[e][2]+bb.z)*xv.z);
        atomicAdd(ap+3, (acc[e][3]+bb.w)*xv.w);
    }
}

// ---------------------------------------------------------------- node update: x = softplus(agg @ nw + nb)
template<int CIN, int LDIN, int NPB>
__global__ __launch_bounds__(256) void node_update_kernel(
    const float* __restrict__ agg, const float* __restrict__ w,
    const float* __restrict__ b, float* __restrict__ xout)
{
    __shared__ float row[NPB][CIN];
    const int n0 = blockIdx.x * NPB;
    for (int idx = threadIdx.x; idx < NPB*CIN; idx += 256){
        const int i = idx / CIN, k = idx - i*CIN;
        row[i][k] = agg[(size_t)(n0+i)*LDIN + k];
    }
    __syncthreads();
    const int c = threadIdx.x;
    float acc[NPB];
    #pragma unroll
    for (int i=0;i<NPB;i++) acc[i] = b[c];
    for (int k=0;k<CIN;k+=4){
        const float w0  = w[(k+0)*HID+c];
        const float w1v = w[(k+1)*HID+c];
        const float w2v = w[(k+2)*HID+c];
        const float w3v = w[(k+3)*HID+c];
        #pragma unroll
        for (int i=0;i<NPB;i++){
            const float4 r = *(const float4*)&row[i][k];
            acc[i] = fmaf(r.x,w0,fmaf(r.y,w1v,fmaf(r.z,w2v,fmaf(r.w,w3v,acc[i]))));
        }
    }
    #pragma unroll
    for (int i=0;i<NPB;i++)
        xout[(size_t)(n0+i)*HID + c] = softplusf(acc[i]);
}

// ---------------------------------------------------------------- mean pool (atomic)
__global__ __launch_bounds__(256) void pool_kernel(
    const float* __restrict__ x, const int* __restrict__ batch,
    float* __restrict__ sums, float* __restrict__ cnts)
{
    const int n = blockIdx.x;
    const int c = threadIdx.x;
    const int g = batch[n];
    atomicAdd(&sums[(size_t)g*HID + c], x[(size_t)n*HID + c]);
    if (c == 0) atomicAdd(&cnts[g], 1.0f);
}

// ---------------------------------------------------------------- readout MLP (one block per graph)
__global__ __launch_bounds__(256) void readout_kernel(
    const float* __restrict__ sums, const float* __restrict__ cnts,
    const float* __restrict__ rw1, const float* __restrict__ rb1,
    const float* __restrict__ rw2, const float* __restrict__ rb2,
    const float* __restrict__ rw3, const float* __restrict__ rb3,
    float* __restrict__ out)
{
    __shared__ float g[HID];
    __shared__ float h[HID];
    __shared__ float h2[HID/2];
    __shared__ float red[256];
    const int gi = blockIdx.x;
    const int t  = threadIdx.x;
    const float cnt = fmaxf(cnts[gi], 1.0f);
    g[t] = sums[(size_t)gi*HID + t] / cnt;
    __syncthreads();
    float acc = rb1[t];
    for (int k=0;k<HID;k++) acc = fmaf(g[k], rw1[(size_t)k*HID + t], acc);
    h[t] = softplusf(acc);
    __syncthreads();
    if (t < HID/2){
        float a2 = rb2[t];
        for (int k=0;k<HID;k++) a2 = fmaf(h[k], rw2[(size_t)k*(HID/2) + t], a2);
        h2[t] = softplusf(a2);
    }
    __syncthreads();
    red[t] = (t < HID/2) ? h2[t]*rw3[t] : 0.0f;
    __syncthreads();
    for (int s2=128; s2>0; s2>>=1){
        if (t < s2) red[t] += red[t+s2];
        __syncthreads();
    }
    if (t == 0) out[gi] = red[0] + rb3[0];
}

// ---------------------------------------------------------------- launcher
extern "C" void kernel_launch(void* const* d_in, const int* in_sizes, int n_in,
                              void* d_out, int out_size, void* d_ws, size_t ws_size,
                              hipStream_t stream)
{
    const int*   x_atoms = (const int*)d_in[0];
    const int*   eidx    = (const int*)d_in[1];
    const int*   src     = eidx;               // edge_index[0]
    const int*   dst     = eidx + N_EDGES;     // edge_index[1]
    const float* ea      = (const float*)d_in[2];
    const int*   batch   = (const int*)d_in[3];
    const float* emb     = (const float*)d_in[4];
    const float* ew1_0   = (const float*)d_in[5];
    const float* eb1_0   = (const float*)d_in[6];
    const float* ew2_0   = (const float*)d_in[7];
    const float* eb2_0   = (const float*)d_in[8];
    const float* nw_0    = (const float*)d_in[9];
    const float* nb_0    = (const float*)d_in[10];
    const float* ew1     = (const float*)d_in[11];
    const float* eb1     = (const float*)d_in[12];
    const float* ew2     = (const float*)d_in[13];
    const float* eb2     = (const float*)d_in[14];
    const float* nw      = (const float*)d_in[15];
    const float* nb      = (const float*)d_in[16];
    const float* rw1     = (const float*)d_in[17];
    const float* rb1     = (const float*)d_in[18];
    const float* rw2     = (const float*)d_in[19];
    const float* rb2     = (const float*)d_in[20];
    const float* rw3     = (const float*)d_in[21];
    const float* rb3     = (const float*)d_in[22];
    float* out = (float*)d_out;

    // workspace layout (fp32): x[N,256] | agg[N,256] | sums[G,256] | cnts[G]  ~51.5 MB
    float* x    = (float*)d_ws;
    float* agg  = x   + (size_t)N_NODES*HID;
    float* sums = agg + (size_t)N_NODES*HID;
    float* cnts = sums + (size_t)N_GRAPHS*HID;

    // ---- layer 0 (C = 92) ----
    hipLaunchKernelGGL(gather_emb_kernel, dim3(N_NODES), dim3(128), 0, stream, x_atoms, emb, x);
    hipMemsetAsync(agg, 0, (size_t)N_NODES*EMB_DIM*sizeof(float), stream);
    hipLaunchKernelGGL((edge_conv92_kernel<16>), dim3(N_EDGES/16), dim3(128), 0, stream,
                       src, dst, ea, ew1_0, eb1_0, ew2_0, eb2_0, x, agg);
    hipLaunchKernelGGL((node_update_kernel<EMB_DIM, EMB_DIM, 4>), dim3(N_NODES/4), dim3(256), 0, stream,
                       agg, nw_0, nb_0, x);

    // ---- layers 1..3 (C = 256) ----
    for (int i=0;i<3;i++){
        hipMemsetAsync(agg, 0, (size_t)N_NODES*HID*sizeof(float), stream);
        hipLaunchKernelGGL((edge_conv256_kernel<16>), dim3(N_EDGES/16), dim3(256), 0, stream,
                           src, dst, ea,
                           ew1 + (size_t)i*4*HID,   eb1 + (size_t)i*HID,
                           ew2 + (size_t)i*HID*HID, eb2 + (size_t)i*HID,
                           x, agg);
        hipLaunchKernelGGL((node_update_kernel<HID, HID, 4>), dim3(N_NODES/4), dim3(256), 0, stream,
                           agg, nw + (size_t)i*HID*HID, nb + (size_t)i*HID, x);
    }

    // ---- pool + readout ----
    hipMemsetAsync(sums, 0, ((size_t)N_GRAPHS*HID + N_GRAPHS)*sizeof(float), stream);
    hipLaunchKernelGGL(pool_kernel, dim3(N_NODES), dim3(HID), 0, stream, x, batch, sums, cnts);
    hipLaunchKernelGGL(readout_kernel, dim3(N_GRAPHS), dim3(256), 0, stream,
                       sums, cnts, rw1, rb1, rw2, rb2, rw3, rb3, out);
}

// Round 2
// 1723.593 us; speedup vs baseline: 2.3696x; 2.3696x over previous
//
#include <hip/hip_runtime.h>
#include <math.h>

#define N_NODES  25000
#define N_EDGES  300000
#define N_GRAPHS 256
#define EMB_DIM  92
#define HID      256

typedef short bf16x8 __attribute__((ext_vector_type(8)));
typedef float f32x4  __attribute__((ext_vector_type(4)));

__device__ __forceinline__ float softplusf(float x){
    // logaddexp(x, 0) == max(x,0) + log1p(exp(-|x|))  (matches jax.nn.softplus)
    return fmaxf(x, 0.0f) + log1pf(expf(-fabsf(x)));
}

__device__ __forceinline__ unsigned short f2bf(float f){
    unsigned int u = __float_as_uint(f);
    unsigned int r = (u + 0x7FFFu + ((u >> 16) & 1u)) >> 16;   // RNE
    return (unsigned short)r;
}
__device__ __forceinline__ float bf2f(unsigned short b){
    return __uint_as_float(((unsigned int)b) << 16);
}

// ---------------------------------------------------------------- embedding gather
__global__ void gather_emb_kernel(const int* __restrict__ atoms,
                                  const float* __restrict__ emb,
                                  float* __restrict__ x)
{
    const int n = blockIdx.x;
    const int c = threadIdx.x;
    if (c < EMB_DIM){
        const int a = atoms[n];
        x[(size_t)n*EMB_DIM + c] = emb[(size_t)a*EMB_DIM + c];
    }
}

// ---------------------------------------------------------------- pack ew2 (3 layers) into MFMA B-fragment layout, hi/lo bf16
// B-frag for mfma_f32_16x16x32_bf16: lane L holds B[k = k8*32 + (L>>4)*8 + j][n = ntile*16 + (L&15)], j=0..7
// fragment id f = (layer*16 + ntile)*8 + k8; storage: frag f at offset f*512 + lane*8 + j (ushort elems)
__global__ __launch_bounds__(256) void pack_w2_kernel(const float* __restrict__ ew2,
                                                      unsigned short* __restrict__ whi,
                                                      unsigned short* __restrict__ wlo)
{
    const int f     = blockIdx.x;          // 0..383
    const int layer = f >> 7;              // /128
    const int rem   = f & 127;
    const int ntile = rem >> 3;
    const int k8    = rem & 7;
    for (int i = threadIdx.x; i < 512; i += 256){
        const int lane = i >> 3, j = i & 7;
        const int k = k8*32 + (lane >> 4)*8 + j;
        const int n = ntile*16 + (lane & 15);
        const float v = ew2[(size_t)layer*HID*HID + (size_t)k*HID + n];
        const unsigned short hb = f2bf(v);
        const float lo = v - bf2f(hb);
        whi[(size_t)f*512 + i] = hb;
        wlo[(size_t)f*512 + i] = f2bf(lo);
    }
}

// ---------------------------------------------------------------- layer-0 edge conv (C=92, fp32)
template<int EPB>
__global__ __launch_bounds__(128) void edge_conv92_kernel(
    const int* __restrict__ src, const int* __restrict__ dst,
    const float* __restrict__ ea,
    const float* __restrict__ w1, const float* __restrict__ b1,
    const float* __restrict__ w2, const float* __restrict__ b2,
    const float* __restrict__ x, float* __restrict__ agg)
{
    constexpr int C = EMB_DIM;
    __shared__ float h1[EPB][C];
    const int e0  = blockIdx.x * EPB;
    const int tid = threadIdx.x;

    for (int idx = tid; idx < EPB*C; idx += 128){
        const int e = idx / C, k = idx - e*C;
        const float4 a = *(const float4*)(ea + (size_t)(e0+e)*4);
        float v = fmaf(a.x, w1[k], fmaf(a.y, w1[C+k], fmaf(a.z, w1[2*C+k], fmaf(a.w, w1[3*C+k], b1[k]))));
        h1[e][k] = softplusf(v);
    }
    __syncthreads();

    const int c = tid;
    if (c < C){
        float acc[EPB];
        #pragma unroll
        for (int e=0;e<EPB;e++) acc[e] = 0.0f;
        for (int k=0;k<C;k+=4){             // 92 = 23*4
            const float w0  = w2[(k+0)*C+c];
            const float w1v = w2[(k+1)*C+c];
            const float w2v = w2[(k+2)*C+c];
            const float w3v = w2[(k+3)*C+c];
            #pragma unroll
            for (int e=0;e<EPB;e++){
                const float4 hv = *(const float4*)&h1[e][k];
                acc[e] = fmaf(hv.x,w0,fmaf(hv.y,w1v,fmaf(hv.z,w2v,fmaf(hv.w,w3v,acc[e]))));
            }
        }
        const float bb = b2[c];
        for (int e=0;e<EPB;e++){
            const int eid = e0 + e;
            const int s = src[eid], d = dst[eid];
            const float msg = (acc[e] + bb) * x[(size_t)s*C + c];
            atomicAdd(&agg[(size_t)d*C + c], msg);
        }
    }
}

// ---------------------------------------------------------------- layers 1-3 edge conv, MFMA split-bf16
// 16 edges per block, 4 waves; wave w covers output cols [w*64, w*64+64), as 4 n-tiles of 16.
__global__ __launch_bounds__(256) void edge_conv256_mfma_kernel(
    const int* __restrict__ src, const int* __restrict__ dst,
    const float* __restrict__ ea,
    const float* __restrict__ w1, const float* __restrict__ b1,
    const unsigned short* __restrict__ whi, const unsigned short* __restrict__ wlo,
    const float* __restrict__ b2,
    const float* __restrict__ x, float* __restrict__ agg)
{
    constexpr int C = HID;
    constexpr int LDA = C + 8;                 // 528 B row stride -> 2-way bank alias (free)
    __shared__ unsigned short aHi[16][LDA];
    __shared__ unsigned short aLo[16][LDA];

    const int e0  = blockIdx.x * 16;
    const int tid = threadIdx.x;

    // phase 1: h1 = softplus(ea @ w1 + b1), split to hi/lo bf16 in LDS (thread = channel)
    {
        const int k = tid;
        const float w10 = w1[k], w11 = w1[C+k], w12 = w1[2*C+k], w13 = w1[3*C+k];
        const float bk = b1[k];
        #pragma unroll
        for (int e=0;e<16;e++){
            const float4 a = *(const float4*)(ea + (size_t)(e0+e)*4);
            const float v = fmaf(a.x,w10,fmaf(a.y,w11,fmaf(a.z,w12,fmaf(a.w,w13,bk))));
            const float h = softplusf(v);
            const unsigned short hb = f2bf(h);
            aHi[e][k] = hb;
            aLo[e][k] = f2bf(h - bf2f(hb));
        }
    }
    __syncthreads();

    // phase 2: [16 x 256] = h1[16 x 256] @ w2[256 x 256] via 16x16x32 bf16 MFMA (hi/lo split)
    const int lane = tid & 63, wv = tid >> 6;
    const int quad = lane >> 4, fcol = lane & 15;

    f32x4 acc[4];
    #pragma unroll
    for (int t=0;t<4;t++){
        #pragma unroll
        for (int j=0;j<4;j++) acc[t][j] = 0.0f;
    }

    const unsigned short* aHrow = &aHi[fcol][0];   // A row m = lane&15
    const unsigned short* aLrow = &aLo[fcol][0];

    for (int k8=0;k8<8;k8++){
        const bf16x8 ah = *(const bf16x8*)(aHrow + k8*32 + quad*8);
        const bf16x8 al = *(const bf16x8*)(aLrow + k8*32 + quad*8);
        #pragma unroll
        for (int t=0;t<4;t++){
            const int fi = (wv*4 + t)*8 + k8;
            const bf16x8 bh = *(const bf16x8*)(whi + (size_t)fi*512 + lane*8);
            const bf16x8 bl = *(const bf16x8*)(wlo + (size_t)fi*512 + lane*8);
            acc[t] = __builtin_amdgcn_mfma_f32_16x16x32_bf16(ah, bh, acc[t], 0, 0, 0);
            acc[t] = __builtin_amdgcn_mfma_f32_16x16x32_bf16(ah, bl, acc[t], 0, 0, 0);
            acc[t] = __builtin_amdgcn_mfma_f32_16x16x32_bf16(al, bh, acc[t], 0, 0, 0);
        }
    }

    // epilogue: C/D layout col = lane&15, row = quad*4 + reg
    #pragma unroll
    for (int i=0;i<4;i++){
        const int eid = e0 + quad*4 + i;
        const int s = src[eid], d = dst[eid];
        #pragma unroll
        for (int t=0;t<4;t++){
            const int n = (wv*4 + t)*16 + fcol;
            const float ee = acc[t][i] + b2[n];
            atomicAdd(&agg[(size_t)d*C + n], ee * x[(size_t)s*C + n]);
        }
    }
}

// ---------------------------------------------------------------- node update: x = softplus(agg @ nw + nb)
template<int CIN, int LDIN, int NPB>
__global__ __launch_bounds__(256) void node_update_kernel(
    const float* __restrict__ agg, const float* __restrict__ w,
    const float* __restrict__ b, float* __restrict__ xout)
{
    __shared__ float row[NPB][CIN];
    const int n0 = blockIdx.x * NPB;
    for (int idx = threadIdx.x; idx < NPB*CIN; idx += 256){
        const int i = idx / CIN, k = idx - i*CIN;
        row[i][k] = agg[(size_t)(n0+i)*LDIN + k];
    }
    __syncthreads();
    const int c = threadIdx.x;
    float acc[NPB];
    #pragma unroll
    for (int i=0;i<NPB;i++) acc[i] = b[c];
    for (int k=0;k<CIN;k+=4){
        const float w0  = w[(k+0)*HID+c];
        const float w1v = w[(k+1)*HID+c];
        const float w2v = w[(k+2)*HID+c];
        const float w3v = w[(k+3)*HID+c];
        #pragma unroll
        for (int i=0;i<NPB;i++){
            const float4 r = *(const float4*)&row[i][k];
            acc[i] = fmaf(r.x,w0,fmaf(r.y,w1v,fmaf(r.z,w2v,fmaf(r.w,w3v,acc[i]))));
        }
    }
    #pragma unroll
    for (int i=0;i<NPB;i++)
        xout[(size_t)(n0+i)*HID + c] = softplusf(acc[i]);
}

// ---------------------------------------------------------------- mean pool (atomic)
__global__ __launch_bounds__(256) void pool_kernel(
    const float* __restrict__ x, const int* __restrict__ batch,
    float* __restrict__ sums, float* __restrict__ cnts)
{
    const int n = blockIdx.x;
    const int c = threadIdx.x;
    const int g = batch[n];
    atomicAdd(&sums[(size_t)g*HID + c], x[(size_t)n*HID + c]);
    if (c == 0) atomicAdd(&cnts[g], 1.0f);
}

// ---------------------------------------------------------------- readout MLP (one block per graph)
__global__ __launch_bounds__(256) void readout_kernel(
    const float* __restrict__ sums, const float* __restrict__ cnts,
    const float* __restrict__ rw1, const float* __restrict__ rb1,
    const float* __restrict__ rw2, const float* __restrict__ rb2,
    const float* __restrict__ rw3, const float* __restrict__ rb3,
    float* __restrict__ out)
{
    __shared__ float g[HID];
    __shared__ float h[HID];
    __shared__ float h2[HID/2];
    __shared__ float red[256];
    const int gi = blockIdx.x;
    const int t  = threadIdx.x;
    const float cnt = fmaxf(cnts[gi], 1.0f);
    g[t] = sums[(size_t)gi*HID + t] / cnt;
    __syncthreads();
    float acc = rb1[t];
    for (int k=0;k<HID;k++) acc = fmaf(g[k], rw1[(size_t)k*HID + t], acc);
    h[t] = softplusf(acc);
    __syncthreads();
    if (t < HID/2){
        float a2 = rb2[t];
        for (int k=0;k<HID;k++) a2 = fmaf(h[k], rw2[(size_t)k*(HID/2) + t], a2);
        h2[t] = softplusf(a2);
    }
    __syncthreads();
    red[t] = (t < HID/2) ? h2[t]*rw3[t] : 0.0f;
    __syncthreads();
    for (int s2=128; s2>0; s2>>=1){
        if (t < s2) red[t] += red[t+s2];
        __syncthreads();
    }
    if (t == 0) out[gi] = red[0] + rb3[0];
}

// ---------------------------------------------------------------- launcher
extern "C" void kernel_launch(void* const* d_in, const int* in_sizes, int n_in,
                              void* d_out, int out_size, void* d_ws, size_t ws_size,
                              hipStream_t stream)
{
    const int*   x_atoms = (const int*)d_in[0];
    const int*   eidx    = (const int*)d_in[1];
    const int*   src     = eidx;               // edge_index[0]
    const int*   dst     = eidx + N_EDGES;     // edge_index[1]
    const float* ea      = (const float*)d_in[2];
    const int*   batch   = (const int*)d_in[3];
    const float* emb     = (const float*)d_in[4];
    const float* ew1_0   = (const float*)d_in[5];
    const float* eb1_0   = (const float*)d_in[6];
    const float* ew2_0   = (const float*)d_in[7];
    const float* eb2_0   = (const float*)d_in[8];
    const float* nw_0    = (const float*)d_in[9];
    const float* nb_0    = (const float*)d_in[10];
    const float* ew1     = (const float*)d_in[11];
    const float* eb1     = (const float*)d_in[12];
    const float* ew2     = (const float*)d_in[13];
    const float* eb2     = (const float*)d_in[14];
    const float* nw      = (const float*)d_in[15];
    const float* nb      = (const float*)d_in[16];
    const float* rw1     = (const float*)d_in[17];
    const float* rb1     = (const float*)d_in[18];
    const float* rw2     = (const float*)d_in[19];
    const float* rb2     = (const float*)d_in[20];
    const float* rw3     = (const float*)d_in[21];
    const float* rb3     = (const float*)d_in[22];
    float* out = (float*)d_out;

    // workspace layout (fp32/u16):
    //   x[N,256] | agg[N,256] | sums[G,256] | cnts[G] | whi[3*128*512 u16] | wlo[...]
    float* x    = (float*)d_ws;
    float* agg  = x   + (size_t)N_NODES*HID;
    float* sums = agg + (size_t)N_NODES*HID;
    float* cnts = sums + (size_t)N_GRAPHS*HID;
    unsigned short* whi = (unsigned short*)(cnts + N_GRAPHS);
    unsigned short* wlo = whi + (size_t)3*128*512;

    // pack weights for MFMA (runs once per launch; ordered on stream)
    hipLaunchKernelGGL(pack_w2_kernel, dim3(384), dim3(256), 0, stream, ew2, whi, wlo);

    // ---- layer 0 (C = 92) ----
    hipLaunchKernelGGL(gather_emb_kernel, dim3(N_NODES), dim3(128), 0, stream, x_atoms, emb, x);
    hipMemsetAsync(agg, 0, (size_t)N_NODES*EMB_DIM*sizeof(float), stream);
    hipLaunchKernelGGL((edge_conv92_kernel<16>), dim3(N_EDGES/16), dim3(128), 0, stream,
                       src, dst, ea, ew1_0, eb1_0, ew2_0, eb2_0, x, agg);
    hipLaunchKernelGGL((node_update_kernel<EMB_DIM, EMB_DIM, 4>), dim3(N_NODES/4), dim3(256), 0, stream,
                       agg, nw_0, nb_0, x);

    // ---- layers 1..3 (C = 256), MFMA ----
    for (int i=0;i<3;i++){
        hipMemsetAsync(agg, 0, (size_t)N_NODES*HID*sizeof(float), stream);
        hipLaunchKernelGGL(edge_conv256_mfma_kernel, dim3(N_EDGES/16), dim3(256), 0, stream,
                           src, dst, ea,
                           ew1 + (size_t)i*4*HID, eb1 + (size_t)i*HID,
                           whi + (size_t)i*128*512, wlo + (size_t)i*128*512,
                           eb2 + (size_t)i*HID,
                           x, agg);
        hipLaunchKernelGGL((node_update_kernel<HID, HID, 4>), dim3(N_NODES/4), dim3(256), 0, stream,
                           agg, nw + (size_t)i*HID*HID, nb + (size_t)i*HID, x);
    }

    // ---- pool + readout ----
    hipMemsetAsync(sums, 0, ((size_t)N_GRAPHS*HID + N_GRAPHS)*sizeof(float), stream);
    hipLaunchKernelGGL(pool_kernel, dim3(N_NODES), dim3(HID), 0, stream, x, batch, sums, cnts);
    hipLaunchKernelGGL(readout_kernel, dim3(N_GRAPHS), dim3(256), 0, stream,
                       sums, cnts, rw1, rb1, rw2, rb2, rw3, rb3, out);
}

// Round 3
// 1509.794 us; speedup vs baseline: 2.7052x; 1.1416x over previous
//
#include <hip/hip_runtime.h>
#include <math.h>

#define N_NODES  25000
#define N_EDGES  300000
#define N_GRAPHS 256
#define EMB_DIM  92
#define HID      256

typedef short bf16x8 __attribute__((ext_vector_type(8)));
typedef float f32x4  __attribute__((ext_vector_type(4)));

__device__ __forceinline__ float softplusf(float x){
    return fmaxf(x, 0.0f) + log1pf(expf(-fabsf(x)));   // == jax.nn.softplus
}
__device__ __forceinline__ unsigned short f2bf(float f){
    unsigned int u = __float_as_uint(f);
    unsigned int r = (u + 0x7FFFu + ((u >> 16) & 1u)) >> 16;   // RNE
    return (unsigned short)r;
}
__device__ __forceinline__ float bf2f(unsigned short b){
    return __uint_as_float(((unsigned int)b) << 16);
}

// ---------------------------------------------------------------- embedding gather
__global__ void gather_emb_kernel(const int* __restrict__ atoms,
                                  const float* __restrict__ emb,
                                  float* __restrict__ x)
{
    const int n = blockIdx.x;
    const int c = threadIdx.x;
    if (c < EMB_DIM){
        const int a = atoms[n];
        x[(size_t)n*EMB_DIM + c] = emb[(size_t)a*EMB_DIM + c];
    }
}

// ---------------------------------------------------------------- counting sort by dst
__global__ __launch_bounds__(256) void hist_kernel(const int* __restrict__ dst, int* __restrict__ hist){
    const int e = blockIdx.x*256 + threadIdx.x;
    if (e < N_EDGES) atomicAdd(&hist[dst[e]], 1);
}

// single block, 1024 threads: exclusive prefix over 25000 bins -> cursor
__global__ __launch_bounds__(1024) void scan_kernel(const int* __restrict__ hist, int* __restrict__ cursor){
    __shared__ int chunk[1024];
    const int t = threadIdx.x;
    const int base = t*25;                     // 1024*25 = 25600 >= 25000
    int local[25];
    int s = 0;
    #pragma unroll
    for (int i=0;i<25;i++){
        const int idx = base+i;
        const int v = (idx < N_NODES) ? hist[idx] : 0;
        local[i] = s; s += v;
    }
    chunk[t] = s;
    __syncthreads();
    for (int off=1; off<1024; off<<=1){
        int v = (t >= off) ? chunk[t-off] : 0;
        __syncthreads();
        chunk[t] += v;
        __syncthreads();
    }
    const int pre = (t > 0) ? chunk[t-1] : 0;
    #pragma unroll
    for (int i=0;i<25;i++){
        const int idx = base+i;
        if (idx < N_NODES) cursor[idx] = pre + local[i];
    }
}

__global__ __launch_bounds__(256) void scatter_kernel(const int* __restrict__ src, const int* __restrict__ dst,
                                                      int* __restrict__ cursor,
                                                      int* __restrict__ perm_s, int* __restrict__ src_s,
                                                      int* __restrict__ dst_s){
    const int e = blockIdx.x*256 + threadIdx.x;
    if (e < N_EDGES){
        const int d = dst[e];
        const int pos = atomicAdd(&cursor[d], 1);
        perm_s[pos] = e;
        src_s[pos]  = src[e];
        dst_s[pos]  = d;
    }
}

// ---------------------------------------------------------------- pack [3][256][256] fp32 weights into MFMA B-frag hi/lo bf16
// frag f = (layer*16 + ntile)*8 + k8; elem: lane L, j -> B[k=k8*32+(L>>4)*8+j][n=ntile*16+(L&15)]
__global__ __launch_bounds__(256) void pack_w_kernel(const float* __restrict__ w,
                                                     unsigned short* __restrict__ whi,
                                                     unsigned short* __restrict__ wlo)
{
    const int f     = blockIdx.x;          // 0..383
    const int layer = f >> 7;
    const int rem   = f & 127;
    const int ntile = rem >> 3;
    const int k8    = rem & 7;
    for (int i = threadIdx.x; i < 512; i += 256){
        const int lane = i >> 3, j = i & 7;
        const int k = k8*32 + (lane >> 4)*8 + j;
        const int n = ntile*16 + (lane & 15);
        const float v = w[(size_t)layer*HID*HID + (size_t)k*HID + n];
        const unsigned short hb = f2bf(v);
        whi[(size_t)f*512 + i] = hb;
        wlo[(size_t)f*512 + i] = f2bf(v - bf2f(hb));
    }
}

// ---------------------------------------------------------------- layer-0 edge conv (C=92, fp32), sorted edges + run merge
__global__ __launch_bounds__(128) void edge_conv92_kernel(
    const int* __restrict__ perm_s, const int* __restrict__ src_s, const int* __restrict__ dst_s,
    const float* __restrict__ ea,
    const float* __restrict__ w1, const float* __restrict__ b1,
    const float* __restrict__ w2, const float* __restrict__ b2,
    const float* __restrict__ x, float* __restrict__ agg)
{
    constexpr int C = EMB_DIM;
    constexpr int EPB = 16;
    __shared__ float h1[EPB][C];
    const int e0  = blockIdx.x * EPB;
    const int tid = threadIdx.x;

    for (int idx = tid; idx < EPB*C; idx += 128){
        const int e = idx / C, k = idx - e*C;
        const float4 a = *(const float4*)(ea + (size_t)perm_s[e0+e]*4);
        float v = fmaf(a.x, w1[k], fmaf(a.y, w1[C+k], fmaf(a.z, w1[2*C+k], fmaf(a.w, w1[3*C+k], b1[k]))));
        h1[e][k] = softplusf(v);
    }
    __syncthreads();

    const int c = tid;
    if (c < C){
        float acc[EPB];
        #pragma unroll
        for (int e=0;e<EPB;e++) acc[e] = 0.0f;
        for (int k=0;k<C;k+=4){             // 92 = 23*4
            const float w0  = w2[(k+0)*C+c];
            const float w1v = w2[(k+1)*C+c];
            const float w2v = w2[(k+2)*C+c];
            const float w3v = w2[(k+3)*C+c];
            #pragma unroll
            for (int e=0;e<EPB;e++){
                const float4 hv = *(const float4*)&h1[e][k];
                acc[e] = fmaf(hv.x,w0,fmaf(hv.y,w1v,fmaf(hv.z,w2v,fmaf(hv.w,w3v,acc[e]))));
            }
        }
        const float bb = b2[c];
        // run-merged scatter (edges sorted by dst)
        int dprev = dst_s[e0];
        float run = 0.0f;
        #pragma unroll
        for (int e=0;e<EPB;e++){
            const int eid = e0 + e;
            const int s = src_s[eid], d = dst_s[eid];
            const float msg = (acc[e] + bb) * x[(size_t)s*C + c];
            if (d != dprev){
                atomicAdd(&agg[(size_t)dprev*C + c], run);
                run = 0.0f; dprev = d;
            }
            run += msg;
        }
        atomicAdd(&agg[(size_t)dprev*C + c], run);
    }
}

// ---------------------------------------------------------------- layers 1-3 edge conv, MFMA split-bf16, 32 edges/block
// 4 waves; wave wv covers cols [wv*64, wv*64+64) (4 n-tiles) x 2 m-tiles (32 edges).
__global__ __launch_bounds__(256) void edge_conv256_mfma_kernel(
    const int* __restrict__ perm_s, const int* __restrict__ src_s, const int* __restrict__ dst_s,
    const float* __restrict__ ea,
    const float* __restrict__ w1, const float* __restrict__ b1,
    const unsigned short* __restrict__ whi, const unsigned short* __restrict__ wlo,
    const float* __restrict__ b2,
    const float* __restrict__ x, float* __restrict__ agg)
{
    constexpr int C = HID;
    constexpr int LDA = C + 8;                 // ushort row stride 528 B
    constexpr int EPB = 32;
    __shared__ unsigned short aHi[EPB][LDA];
    __shared__ unsigned short aLo[EPB][LDA];

    const int e0  = blockIdx.x * EPB;
    const int tid = threadIdx.x;

    // phase 1: h1 = softplus(ea[perm] @ w1 + b1) -> hi/lo bf16 LDS
    {
        const int k = tid;
        const float w10 = w1[k], w11 = w1[C+k], w12 = w1[2*C+k], w13 = w1[3*C+k];
        const float bk = b1[k];
        #pragma unroll
        for (int e=0;e<EPB;e++){
            const float4 a = *(const float4*)(ea + (size_t)perm_s[e0+e]*4);
            const float v = fmaf(a.x,w10,fmaf(a.y,w11,fmaf(a.z,w12,fmaf(a.w,w13,bk))));
            const float h = softplusf(v);
            const unsigned short hb = f2bf(h);
            aHi[e][k] = hb;
            aLo[e][k] = f2bf(h - bf2f(hb));
        }
    }
    __syncthreads();

    const int lane = tid & 63, wv = tid >> 6;
    const int quad = lane >> 4, fcol = lane & 15;

    f32x4 acc[2][4];
    #pragma unroll
    for (int m=0;m<2;m++)
        #pragma unroll
        for (int t=0;t<4;t++)
            #pragma unroll
            for (int j=0;j<4;j++) acc[m][t][j] = 0.0f;

    for (int k8=0;k8<8;k8++){
        bf16x8 ah[2], al[2];
        #pragma unroll
        for (int m=0;m<2;m++){
            ah[m] = *(const bf16x8*)(&aHi[m*16 + fcol][0] + k8*32 + quad*8);
            al[m] = *(const bf16x8*)(&aLo[m*16 + fcol][0] + k8*32 + quad*8);
        }
        #pragma unroll
        for (int t=0;t<4;t++){
            const int fi = (wv*4 + t)*8 + k8;
            const bf16x8 bh = *(const bf16x8*)(whi + (size_t)fi*512 + lane*8);
            const bf16x8 bl = *(const bf16x8*)(wlo + (size_t)fi*512 + lane*8);
            #pragma unroll
            for (int m=0;m<2;m++){
                acc[m][t] = __builtin_amdgcn_mfma_f32_16x16x32_bf16(ah[m], bh, acc[m][t], 0, 0, 0);
                acc[m][t] = __builtin_amdgcn_mfma_f32_16x16x32_bf16(ah[m], bl, acc[m][t], 0, 0, 0);
                acc[m][t] = __builtin_amdgcn_mfma_f32_16x16x32_bf16(al[m], bh, acc[m][t], 0, 0, 0);
            }
        }
    }

    // epilogue: C/D layout col = lane&15 (n), row = quad*4 + reg (edge); run-merge sorted dsts
    float bb[4];
    #pragma unroll
    for (int t=0;t<4;t++) bb[t] = b2[(wv*4 + t)*16 + fcol];

    #pragma unroll
    for (int m=0;m<2;m++){
        const int ebase = e0 + m*16 + quad*4;
        int dprev = dst_s[ebase];
        float run[4] = {0.f,0.f,0.f,0.f};
        #pragma unroll
        for (int i=0;i<4;i++){
            const int eid = ebase + i;
            const int s = src_s[eid], d = dst_s[eid];
            if (d != dprev){
                #pragma unroll
                for (int t=0;t<4;t++){
                    const int n = (wv*4 + t)*16 + fcol;
                    atomicAdd(&agg[(size_t)dprev*C + n], run[t]);
                    run[t] = 0.0f;
                }
                dprev = d;
            }
            #pragma unroll
            for (int t=0;t<4;t++){
                const int n = (wv*4 + t)*16 + fcol;
                run[t] += (acc[m][t][i] + bb[t]) * x[(size_t)s*C + n];
            }
        }
        #pragma unroll
        for (int t=0;t<4;t++){
            const int n = (wv*4 + t)*16 + fcol;
            atomicAdd(&agg[(size_t)dprev*C + n], run[t]);
        }
    }
}

// ---------------------------------------------------------------- node update MFMA (CIN=256): x = softplus(agg @ nw + nb)
__global__ __launch_bounds__(256) void node_update_mfma_kernel(
    const float* __restrict__ agg,
    const unsigned short* __restrict__ whi, const unsigned short* __restrict__ wlo,
    const float* __restrict__ b, float* __restrict__ xout)
{
    constexpr int C = HID;
    constexpr int LDA = C + 8;
    __shared__ unsigned short aHi[16][LDA];
    __shared__ unsigned short aLo[16][LDA];

    const int n0  = blockIdx.x * 16;
    const int tid = threadIdx.x;

    #pragma unroll
    for (int it=0; it<16; it++){
        const int row = it, k = tid;
        const int node = n0 + row;
        const float v = (node < N_NODES) ? agg[(size_t)node*C + k] : 0.0f;
        const unsigned short hb = f2bf(v);
        aHi[row][k] = hb;
        aLo[row][k] = f2bf(v - bf2f(hb));
    }
    __syncthreads();

    const int lane = tid & 63, wv = tid >> 6;
    const int quad = lane >> 4, fcol = lane & 15;

    f32x4 acc[4];
    #pragma unroll
    for (int t=0;t<4;t++)
        #pragma unroll
        for (int j=0;j<4;j++) acc[t][j] = 0.0f;

    const unsigned short* aHrow = &aHi[fcol][0];
    const unsigned short* aLrow = &aLo[fcol][0];

    for (int k8=0;k8<8;k8++){
        const bf16x8 ah = *(const bf16x8*)(aHrow + k8*32 + quad*8);
        const bf16x8 al = *(const bf16x8*)(aLrow + k8*32 + quad*8);
        #pragma unroll
        for (int t=0;t<4;t++){
            const int fi = (wv*4 + t)*8 + k8;
            const bf16x8 bh = *(const bf16x8*)(whi + (size_t)fi*512 + lane*8);
            const bf16x8 bl = *(const bf16x8*)(wlo + (size_t)fi*512 + lane*8);
            acc[t] = __builtin_amdgcn_mfma_f32_16x16x32_bf16(ah, bh, acc[t], 0, 0, 0);
            acc[t] = __builtin_amdgcn_mfma_f32_16x16x32_bf16(ah, bl, acc[t], 0, 0, 0);
            acc[t] = __builtin_amdgcn_mfma_f32_16x16x32_bf16(al, bh, acc[t], 0, 0, 0);
        }
    }

    #pragma unroll
    for (int i=0;i<4;i++){
        const int node = n0 + quad*4 + i;
        if (node < N_NODES){
            #pragma unroll
            for (int t=0;t<4;t++){
                const int n = (wv*4 + t)*16 + fcol;
                xout[(size_t)node*C + n] = softplusf(acc[t][i] + b[n]);
            }
        }
    }
}

// ---------------------------------------------------------------- node update fp32 (layer 0, CIN=92)
__global__ __launch_bounds__(256) void node_update92_kernel(
    const float* __restrict__ agg, const float* __restrict__ w,
    const float* __restrict__ b, float* __restrict__ xout)
{
    constexpr int CIN = EMB_DIM, NPB = 4;
    __shared__ float row[NPB][CIN];
    const int n0 = blockIdx.x * NPB;
    for (int idx = threadIdx.x; idx < NPB*CIN; idx += 256){
        const int i = idx / CIN, k = idx - i*CIN;
        row[i][k] = agg[(size_t)(n0+i)*CIN + k];
    }
    __syncthreads();
    const int c = threadIdx.x;
    float acc[NPB];
    #pragma unroll
    for (int i=0;i<NPB;i++) acc[i] = b[c];
    for (int k=0;k<CIN;k+=4){
        const float w0  = w[(k+0)*HID+c];
        const float w1v = w[(k+1)*HID+c];
        const float w2v = w[(k+2)*HID+c];
        const float w3v = w[(k+3)*HID+c];
        #pragma unroll
        for (int i=0;i<NPB;i++){
            const float4 r = *(const float4*)&row[i][k];
            acc[i] = fmaf(r.x,w0,fmaf(r.y,w1v,fmaf(r.z,w2v,fmaf(r.w,w3v,acc[i]))));
        }
    }
    #pragma unroll
    for (int i=0;i<NPB;i++)
        xout[(size_t)(n0+i)*HID + c] = softplusf(acc[i]);
}

// ---------------------------------------------------------------- mean pool, run-merged (batch is sorted)
__global__ __launch_bounds__(256) void pool_kernel(
    const float* __restrict__ x, const int* __restrict__ batch,
    float* __restrict__ sums, float* __restrict__ cnts)
{
    constexpr int NPB = 32;
    const int n0 = blockIdx.x * NPB;
    const int c  = threadIdx.x;
    int gprev = batch[n0];
    float run = 0.0f, crun = 0.0f;
    for (int i=0;i<NPB;i++){
        const int n = n0 + i;
        if (n >= N_NODES) break;
        const int g = batch[n];
        if (g != gprev){
            atomicAdd(&sums[(size_t)gprev*HID + c], run);
            if (c == 0) atomicAdd(&cnts[gprev], crun);
            run = 0.0f; crun = 0.0f; gprev = g;
        }
        run  += x[(size_t)n*HID + c];
        crun += 1.0f;
    }
    atomicAdd(&sums[(size_t)gprev*HID + c], run);
    if (c == 0) atomicAdd(&cnts[gprev], crun);
}

// ---------------------------------------------------------------- readout MLP (one block per graph)
__global__ __launch_bounds__(256) void readout_kernel(
    const float* __restrict__ sums, const float* __restrict__ cnts,
    const float* __restrict__ rw1, const float* __restrict__ rb1,
    const float* __restrict__ rw2, const float* __restrict__ rb2,
    const float* __restrict__ rw3, const float* __restrict__ rb3,
    float* __restrict__ out)
{
    __shared__ float g[HID];
    __shared__ float h[HID];
    __shared__ float h2[HID/2];
    __shared__ float red[256];
    const int gi = blockIdx.x;
    const int t  = threadIdx.x;
    const float cnt = fmaxf(cnts[gi], 1.0f);
    g[t] = sums[(size_t)gi*HID + t] / cnt;
    __syncthreads();
    float acc = rb1[t];
    for (int k=0;k<HID;k++) acc = fmaf(g[k], rw1[(size_t)k*HID + t], acc);
    h[t] = softplusf(acc);
    __syncthreads();
    if (t < HID/2){
        float a2 = rb2[t];
        for (int k=0;k<HID;k++) a2 = fmaf(h[k], rw2[(size_t)k*(HID/2) + t], a2);
        h2[t] = softplusf(a2);
    }
    __syncthreads();
    red[t] = (t < HID/2) ? h2[t]*rw3[t] : 0.0f;
    __syncthreads();
    for (int s2=128; s2>0; s2>>=1){
        if (t < s2) red[t] += red[t+s2];
        __syncthreads();
    }
    if (t == 0) out[gi] = red[0] + rb3[0];
}

// ---------------------------------------------------------------- launcher
extern "C" void kernel_launch(void* const* d_in, const int* in_sizes, int n_in,
                              void* d_out, int out_size, void* d_ws, size_t ws_size,
                              hipStream_t stream)
{
    const int*   x_atoms = (const int*)d_in[0];
    const int*   eidx    = (const int*)d_in[1];
    const int*   src     = eidx;               // edge_index[0]
    const int*   dst     = eidx + N_EDGES;     // edge_index[1]
    const float* ea      = (const float*)d_in[2];
    const int*   batch   = (const int*)d_in[3];
    const float* emb     = (const float*)d_in[4];
    const float* ew1_0   = (const float*)d_in[5];
    const float* eb1_0   = (const float*)d_in[6];
    const float* ew2_0   = (const float*)d_in[7];
    const float* eb2_0   = (const float*)d_in[8];
    const float* nw_0    = (const float*)d_in[9];
    const float* nb_0    = (const float*)d_in[10];
    const float* ew1     = (const float*)d_in[11];
    const float* eb1     = (const float*)d_in[12];
    const float* ew2     = (const float*)d_in[13];
    const float* eb2     = (const float*)d_in[14];
    const float* nw      = (const float*)d_in[15];
    const float* nb      = (const float*)d_in[16];
    const float* rw1     = (const float*)d_in[17];
    const float* rb1     = (const float*)d_in[18];
    const float* rw2     = (const float*)d_in[19];
    const float* rb2     = (const float*)d_in[20];
    const float* rw3     = (const float*)d_in[21];
    const float* rb3     = (const float*)d_in[22];
    float* out = (float*)d_out;

    // workspace layout:
    // x[N*256] | agg[N*256] | sums[G*256] | cnts[G] | whi|wlo|nwhi|nwlo (3*128*512 u16 each)
    // | hist[25000] | cursor[25000] | perm_s|src_s|dst_s (300000 int each)    ~56.9 MB
    float* x    = (float*)d_ws;
    float* agg  = x   + (size_t)N_NODES*HID;
    float* sums = agg + (size_t)N_NODES*HID;
    float* cnts = sums + (size_t)N_GRAPHS*HID;
    unsigned short* whi  = (unsigned short*)(cnts + N_GRAPHS);
    unsigned short* wlo  = whi  + (size_t)3*128*512;
    unsigned short* nwhi = wlo  + (size_t)3*128*512;
    unsigned short* nwlo = nwhi + (size_t)3*128*512;
    int* hist   = (int*)(nwlo + (size_t)3*128*512);
    int* cursor = hist   + N_NODES;
    int* perm_s = cursor + N_NODES;
    int* src_s  = perm_s + N_EDGES;
    int* dst_s  = src_s  + N_EDGES;

    // ---- counting sort of edges by dst (once per launch) ----
    hipMemsetAsync(hist, 0, N_NODES*sizeof(int), stream);
    hipLaunchKernelGGL(hist_kernel, dim3((N_EDGES+255)/256), dim3(256), 0, stream, dst, hist);
    hipLaunchKernelGGL(scan_kernel, dim3(1), dim3(1024), 0, stream, hist, cursor);
    hipLaunchKernelGGL(scatter_kernel, dim3((N_EDGES+255)/256), dim3(256), 0, stream,
                       src, dst, cursor, perm_s, src_s, dst_s);

    // ---- pack weights for MFMA ----
    hipLaunchKernelGGL(pack_w_kernel, dim3(384), dim3(256), 0, stream, ew2, whi, wlo);
    hipLaunchKernelGGL(pack_w_kernel, dim3(384), dim3(256), 0, stream, nw, nwhi, nwlo);

    // ---- layer 0 (C = 92) ----
    hipLaunchKernelGGL(gather_emb_kernel, dim3(N_NODES), dim3(128), 0, stream, x_atoms, emb, x);
    hipMemsetAsync(agg, 0, (size_t)N_NODES*EMB_DIM*sizeof(float), stream);
    hipLaunchKernelGGL(edge_conv92_kernel, dim3(N_EDGES/16), dim3(128), 0, stream,
                       perm_s, src_s, dst_s, ea, ew1_0, eb1_0, ew2_0, eb2_0, x, agg);
    hipLaunchKernelGGL(node_update92_kernel, dim3(N_NODES/4), dim3(256), 0, stream,
                       agg, nw_0, nb_0, x);

    // ---- layers 1..3 (C = 256), MFMA ----
    for (int i=0;i<3;i++){
        hipMemsetAsync(agg, 0, (size_t)N_NODES*HID*sizeof(float), stream);
        hipLaunchKernelGGL(edge_conv256_mfma_kernel, dim3(N_EDGES/32), dim3(256), 0, stream,
                           perm_s, src_s, dst_s, ea,
                           ew1 + (size_t)i*4*HID, eb1 + (size_t)i*HID,
                           whi + (size_t)i*128*512, wlo + (size_t)i*128*512,
                           eb2 + (size_t)i*HID,
                           x, agg);
        hipLaunchKernelGGL(node_update_mfma_kernel, dim3((N_NODES+15)/16), dim3(256), 0, stream,
                           agg, nwhi + (size_t)i*128*512, nwlo + (size_t)i*128*512,
                           nb + (size_t)i*HID, x);
    }

    // ---- pool + readout ----
    hipMemsetAsync(sums, 0, ((size_t)N_GRAPHS*HID + N_GRAPHS)*sizeof(float), stream);
    hipLaunchKernelGGL(pool_kernel, dim3((N_NODES+31)/32), dim3(256), 0, stream, x, batch, sums, cnts);
    hipLaunchKernelGGL(readout_kernel, dim3(N_GRAPHS), dim3(256), 0, stream,
                       sums, cnts, rw1, rb1, rw2, rb2, rw3, rb3, out);
}

// Round 4
// 1339.190 us; speedup vs baseline: 3.0498x; 1.1274x over previous
//
#include <hip/hip_runtime.h>
#include <math.h>

#define N_NODES  25000
#define N_EDGES  300000
#define N_GRAPHS 256
#define EMB_DIM  92
#define HID      256

typedef short bf16x8 __attribute__((ext_vector_type(8)));
typedef float f32x4  __attribute__((ext_vector_type(4)));

// fast softplus == jax.nn.softplus to ~1e-6 abs: max(x,0) + log(1+exp(-|x|))
__device__ __forceinline__ float softplusf(float x){
    return fmaxf(x, 0.0f) + __logf(1.0f + __expf(-fabsf(x)));
}
// RNE f2bf (used only in once-per-launch weight packing)
__device__ __forceinline__ unsigned short f2bf(float f){
    unsigned int u = __float_as_uint(f);
    unsigned int r = (u + 0x7FFFu + ((u >> 16) & 1u)) >> 16;
    return (unsigned short)r;
}
__device__ __forceinline__ float bf2f(unsigned short b){
    return __uint_as_float(((unsigned int)b) << 16);
}
// cheap hi/lo split by truncation: h = hi + r exactly; lo = trunc16(r).
// total representation error <= 2^-16 |h| — absorbed by 3-term MFMA scheme.
__device__ __forceinline__ void split_bf(float h, unsigned short& hi, unsigned short& lo){
    const unsigned int u = __float_as_uint(h);
    hi = (unsigned short)(u >> 16);
    const float r = h - __uint_as_float(u & 0xFFFF0000u);
    lo = (unsigned short)(__float_as_uint(r) >> 16);
}

// ---------------------------------------------------------------- embedding gather
__global__ void gather_emb_kernel(const int* __restrict__ atoms,
                                  const float* __restrict__ emb,
                                  float* __restrict__ x)
{
    const int n = blockIdx.x;
    const int c = threadIdx.x;
    if (c < EMB_DIM){
        const int a = atoms[n];
        x[(size_t)n*EMB_DIM + c] = emb[(size_t)a*EMB_DIM + c];
    }
}

// ---------------------------------------------------------------- counting sort by dst
__global__ __launch_bounds__(256) void hist_kernel(const int* __restrict__ dst, int* __restrict__ hist){
    const int e = blockIdx.x*256 + threadIdx.x;
    if (e < N_EDGES) atomicAdd(&hist[dst[e]], 1);
}

__global__ __launch_bounds__(1024) void scan_kernel(const int* __restrict__ hist, int* __restrict__ cursor){
    __shared__ int chunk[1024];
    const int t = threadIdx.x;
    const int base = t*25;                     // 1024*25 = 25600 >= 25000
    int local[25];
    int s = 0;
    #pragma unroll
    for (int i=0;i<25;i++){
        const int idx = base+i;
        const int v = (idx < N_NODES) ? hist[idx] : 0;
        local[i] = s; s += v;
    }
    chunk[t] = s;
    __syncthreads();
    for (int off=1; off<1024; off<<=1){
        int v = (t >= off) ? chunk[t-off] : 0;
        __syncthreads();
        chunk[t] += v;
        __syncthreads();
    }
    const int pre = (t > 0) ? chunk[t-1] : 0;
    #pragma unroll
    for (int i=0;i<25;i++){
        const int idx = base+i;
        if (idx < N_NODES) cursor[idx] = pre + local[i];
    }
}

__global__ __launch_bounds__(256) void scatter_kernel(const int* __restrict__ src, const int* __restrict__ dst,
                                                      int* __restrict__ cursor,
                                                      int* __restrict__ perm_s, int* __restrict__ src_s,
                                                      int* __restrict__ dst_s){
    const int e = blockIdx.x*256 + threadIdx.x;
    if (e < N_EDGES){
        const int d = dst[e];
        const int pos = atomicAdd(&cursor[d], 1);
        perm_s[pos] = e;
        src_s[pos]  = src[e];
        dst_s[pos]  = d;
    }
}

// ---------------------------------------------------------------- pack [3][256][256] fp32 weights into MFMA B-frag hi/lo bf16
__global__ __launch_bounds__(256) void pack_w_kernel(const float* __restrict__ w,
                                                     unsigned short* __restrict__ whi,
                                                     unsigned short* __restrict__ wlo)
{
    const int f     = blockIdx.x;          // 0..383
    const int layer = f >> 7;
    const int rem   = f & 127;
    const int ntile = rem >> 3;
    const int k8    = rem & 7;
    for (int i = threadIdx.x; i < 512; i += 256){
        const int lane = i >> 3, j = i & 7;
        const int k = k8*32 + (lane >> 4)*8 + j;
        const int n = ntile*16 + (lane & 15);
        const float v = w[(size_t)layer*HID*HID + (size_t)k*HID + n];
        const unsigned short hb = f2bf(v);
        whi[(size_t)f*512 + i] = hb;
        wlo[(size_t)f*512 + i] = f2bf(v - bf2f(hb));
    }
}

// ---------------------------------------------------------------- layer-0 edge conv (C=92, fp32), sorted edges + run merge
__global__ __launch_bounds__(128) void edge_conv92_kernel(
    const int* __restrict__ perm_s, const int* __restrict__ src_s, const int* __restrict__ dst_s,
    const float* __restrict__ ea,
    const float* __restrict__ w1, const float* __restrict__ b1,
    const float* __restrict__ w2, const float* __restrict__ b2,
    const float* __restrict__ x, float* __restrict__ agg)
{
    constexpr int C = EMB_DIM;
    constexpr int EPB = 16;
    __shared__ float h1[EPB][C];
    const int e0  = blockIdx.x * EPB;
    const int tid = threadIdx.x;

    for (int idx = tid; idx < EPB*C; idx += 128){
        const int e = idx / C, k = idx - e*C;
        const float4 a = *(const float4*)(ea + (size_t)perm_s[e0+e]*4);
        float v = fmaf(a.x, w1[k], fmaf(a.y, w1[C+k], fmaf(a.z, w1[2*C+k], fmaf(a.w, w1[3*C+k], b1[k]))));
        h1[e][k] = softplusf(v);
    }
    __syncthreads();

    const int c = tid;
    if (c < C){
        float acc[EPB];
        #pragma unroll
        for (int e=0;e<EPB;e++) acc[e] = 0.0f;
        for (int k=0;k<C;k+=4){             // 92 = 23*4
            const float w0  = w2[(k+0)*C+c];
            const float w1v = w2[(k+1)*C+c];
            const float w2v = w2[(k+2)*C+c];
            const float w3v = w2[(k+3)*C+c];
            #pragma unroll
            for (int e=0;e<EPB;e++){
                const float4 hv = *(const float4*)&h1[e][k];
                acc[e] = fmaf(hv.x,w0,fmaf(hv.y,w1v,fmaf(hv.z,w2v,fmaf(hv.w,w3v,acc[e]))));
            }
        }
        const float bb = b2[c];
        int dprev = dst_s[e0];
        float run = 0.0f;
        #pragma unroll
        for (int e=0;e<EPB;e++){
            const int eid = e0 + e;
            const int s = src_s[eid], d = dst_s[eid];
            const float msg = (acc[e] + bb) * x[(size_t)s*C + c];
            if (d != dprev){
                atomicAdd(&agg[(size_t)dprev*C + c], run);
                run = 0.0f; dprev = d;
            }
            run += msg;
        }
        atomicAdd(&agg[(size_t)dprev*C + c], run);
    }
}

// ---------------------------------------------------------------- layers 1-3 edge conv, MFMA split-bf16, 32 edges/block
__global__ __launch_bounds__(256) void edge_conv256_mfma_kernel(
    const int* __restrict__ perm_s, const int* __restrict__ src_s, const int* __restrict__ dst_s,
    const float* __restrict__ ea,
    const float* __restrict__ w1, const float* __restrict__ b1,
    const unsigned short* __restrict__ whi, const unsigned short* __restrict__ wlo,
    const float* __restrict__ b2,
    const float* __restrict__ x, float* __restrict__ agg)
{
    constexpr int C = HID;
    constexpr int LDA = C + 8;                 // ushort row stride 528 B -> 2-way bank alias (free)
    constexpr int EPB = 32;
    __shared__ unsigned short aHi[EPB][LDA];
    __shared__ unsigned short aLo[EPB][LDA];

    const int e0  = blockIdx.x * EPB;
    const int tid = threadIdx.x;

    // phase 1: h1 = softplus(ea[perm] @ w1 + b1) -> hi/lo bf16 LDS (thread = channel)
    {
        const int k = tid;
        const float w10 = w1[k], w11 = w1[C+k], w12 = w1[2*C+k], w13 = w1[3*C+k];
        const float bk = b1[k];
        #pragma unroll
        for (int e=0;e<EPB;e++){
            const float4 a = *(const float4*)(ea + (size_t)perm_s[e0+e]*4);
            const float v = fmaf(a.x,w10,fmaf(a.y,w11,fmaf(a.z,w12,fmaf(a.w,w13,bk))));
            const float h = softplusf(v);
            unsigned short hb, lb;
            split_bf(h, hb, lb);
            aHi[e][k] = hb;
            aLo[e][k] = lb;
        }
    }
    __syncthreads();

    const int lane = tid & 63, wv = tid >> 6;
    const int quad = lane >> 4, fcol = lane & 15;

    f32x4 acc[2][4];
    #pragma unroll
    for (int m=0;m<2;m++)
        #pragma unroll
        for (int t=0;t<4;t++)
            #pragma unroll
            for (int j=0;j<4;j++) acc[m][t][j] = 0.0f;

    for (int k8=0;k8<8;k8++){
        bf16x8 ah[2], al[2];
        #pragma unroll
        for (int m=0;m<2;m++){
            ah[m] = *(const bf16x8*)(&aHi[m*16 + fcol][0] + k8*32 + quad*8);
            al[m] = *(const bf16x8*)(&aLo[m*16 + fcol][0] + k8*32 + quad*8);
        }
        #pragma unroll
        for (int t=0;t<4;t++){
            const int fi = (wv*4 + t)*8 + k8;
            const bf16x8 bh = *(const bf16x8*)(whi + (size_t)fi*512 + lane*8);
            const bf16x8 bl = *(const bf16x8*)(wlo + (size_t)fi*512 + lane*8);
            #pragma unroll
            for (int m=0;m<2;m++){
                acc[m][t] = __builtin_amdgcn_mfma_f32_16x16x32_bf16(ah[m], bh, acc[m][t], 0, 0, 0);
                acc[m][t] = __builtin_amdgcn_mfma_f32_16x16x32_bf16(ah[m], bl, acc[m][t], 0, 0, 0);
                acc[m][t] = __builtin_amdgcn_mfma_f32_16x16x32_bf16(al[m], bh, acc[m][t], 0, 0, 0);
            }
        }
    }

    // epilogue: C/D layout col = lane&15 (n), row = quad*4 + reg (edge); run-merge sorted dsts
    float bb[4];
    #pragma unroll
    for (int t=0;t<4;t++) bb[t] = b2[(wv*4 + t)*16 + fcol];

    #pragma unroll
    for (int m=0;m<2;m++){
        const int ebase = e0 + m*16 + quad*4;
        int dprev = dst_s[ebase];
        float run[4] = {0.f,0.f,0.f,0.f};
        #pragma unroll
        for (int i=0;i<4;i++){
            const int eid = ebase + i;
            const int s = src_s[eid], d = dst_s[eid];
            if (d != dprev){
                #pragma unroll
                for (int t=0;t<4;t++){
                    const int n = (wv*4 + t)*16 + fcol;
                    atomicAdd(&agg[(size_t)dprev*C + n], run[t]);
                    run[t] = 0.0f;
                }
                dprev = d;
            }
            #pragma unroll
            for (int t=0;t<4;t++){
                const int n = (wv*4 + t)*16 + fcol;
                run[t] += (acc[m][t][i] + bb[t]) * x[(size_t)s*C + n];
            }
        }
        #pragma unroll
        for (int t=0;t<4;t++){
            const int n = (wv*4 + t)*16 + fcol;
            atomicAdd(&agg[(size_t)dprev*C + n], run[t]);
        }
    }
}

// ---------------------------------------------------------------- node update MFMA (CIN=256): x = softplus(agg @ nw + nb)
__global__ __launch_bounds__(256) void node_update_mfma_kernel(
    const float* __restrict__ agg,
    const unsigned short* __restrict__ whi, const unsigned short* __restrict__ wlo,
    const float* __restrict__ b, float* __restrict__ xout)
{
    constexpr int C = HID;
    constexpr int LDA = C + 8;
    __shared__ unsigned short aHi[16][LDA];
    __shared__ unsigned short aLo[16][LDA];

    const int n0  = blockIdx.x * 16;
    const int tid = threadIdx.x;

    #pragma unroll
    for (int it=0; it<16; it++){
        const int row = it, k = tid;
        const int node = n0 + row;
        const float v = (node < N_NODES) ? agg[(size_t)node*C + k] : 0.0f;
        unsigned short hb, lb;
        split_bf(v, hb, lb);
        aHi[row][k] = hb;
        aLo[row][k] = lb;
    }
    __syncthreads();

    const int lane = tid & 63, wv = tid >> 6;
    const int quad = lane >> 4, fcol = lane & 15;

    f32x4 acc[4];
    #pragma unroll
    for (int t=0;t<4;t++)
        #pragma unroll
        for (int j=0;j<4;j++) acc[t][j] = 0.0f;

    const unsigned short* aHrow = &aHi[fcol][0];
    const unsigned short* aLrow = &aLo[fcol][0];

    for (int k8=0;k8<8;k8++){
        const bf16x8 ah = *(const bf16x8*)(aHrow + k8*32 + quad*8);
        const bf16x8 al = *(const bf16x8*)(aLrow + k8*32 + quad*8);
        #pragma unroll
        for (int t=0;t<4;t++){
            const int fi = (wv*4 + t)*8 + k8;
            const bf16x8 bh = *(const bf16x8*)(whi + (size_t)fi*512 + lane*8);
            const bf16x8 bl = *(const bf16x8*)(wlo + (size_t)fi*512 + lane*8);
            acc[t] = __builtin_amdgcn_mfma_f32_16x16x32_bf16(ah, bh, acc[t], 0, 0, 0);
            acc[t] = __builtin_amdgcn_mfma_f32_16x16x32_bf16(ah, bl, acc[t], 0, 0, 0);
            acc[t] = __builtin_amdgcn_mfma_f32_16x16x32_bf16(al, bh, acc[t], 0, 0, 0);
        }
    }

    #pragma unroll
    for (int i=0;i<4;i++){
        const int node = n0 + quad*4 + i;
        if (node < N_NODES){
            #pragma unroll
            for (int t=0;t<4;t++){
                const int n = (wv*4 + t)*16 + fcol;
                xout[(size_t)node*C + n] = softplusf(acc[t][i] + b[n]);
            }
        }
    }
}

// ---------------------------------------------------------------- node update fp32 (layer 0, CIN=92)
__global__ __launch_bounds__(256) void node_update92_kernel(
    const float* __restrict__ agg, const float* __restrict__ w,
    const float* __restrict__ b, float* __restrict__ xout)
{
    constexpr int CIN = EMB_DIM, NPB = 4;
    __shared__ float row[NPB][CIN];
    const int n0 = blockIdx.x * NPB;
    for (int idx = threadIdx.x; idx < NPB*CIN; idx += 256){
        const int i = idx / CIN, k = idx - i*CIN;
        row[i][k] = agg[(size_t)(n0+i)*CIN + k];
    }
    __syncthreads();
    const int c = threadIdx.x;
    float acc[NPB];
    #pragma unroll
    for (int i=0;i<NPB;i++) acc[i] = b[c];
    for (int k=0;k<CIN;k+=4){
        const float w0  = w[(k+0)*HID+c];
        const float w1v = w[(k+1)*HID+c];
        const float w2v = w[(k+2)*HID+c];
        const float w3v = w[(k+3)*HID+c];
        #pragma unroll
        for (int i=0;i<NPB;i++){
            const float4 r = *(const float4*)&row[i][k];
            acc[i] = fmaf(r.x,w0,fmaf(r.y,w1v,fmaf(r.z,w2v,fmaf(r.w,w3v,acc[i]))));
        }
    }
    #pragma unroll
    for (int i=0;i<NPB;i++)
        xout[(size_t)(n0+i)*HID + c] = softplusf(acc[i]);
}

// ---------------------------------------------------------------- mean pool, run-merged (batch is sorted)
__global__ __launch_bounds__(256) void pool_kernel(
    const float* __restrict__ x, const int* __restrict__ batch,
    float* __restrict__ sums, float* __restrict__ cnts)
{
    constexpr int NPB = 32;
    const int n0 = blockIdx.x * NPB;
    const int c  = threadIdx.x;
    int gprev = batch[n0];
    float run = 0.0f, crun = 0.0f;
    for (int i=0;i<NPB;i++){
        const int n = n0 + i;
        if (n >= N_NODES) break;
        const int g = batch[n];
        if (g != gprev){
            atomicAdd(&sums[(size_t)gprev*HID + c], run);
            if (c == 0) atomicAdd(&cnts[gprev], crun);
            run = 0.0f; crun = 0.0f; gprev = g;
        }
        run  += x[(size_t)n*HID + c];
        crun += 1.0f;
    }
    atomicAdd(&sums[(size_t)gprev*HID + c], run);
    if (c == 0) atomicAdd(&cnts[gprev], crun);
}

// ---------------------------------------------------------------- readout MLP (one block per graph)
__global__ __launch_bounds__(256) void readout_kernel(
    const float* __restrict__ sums, const float* __restrict__ cnts,
    const float* __restrict__ rw1, const float* __restrict__ rb1,
    const float* __restrict__ rw2, const float* __restrict__ rb2,
    const float* __restrict__ rw3, const float* __restrict__ rb3,
    float* __restrict__ out)
{
    __shared__ float g[HID];
    __shared__ float h[HID];
    __shared__ float h2[HID/2];
    __shared__ float red[256];
    const int gi = blockIdx.x;
    const int t  = threadIdx.x;
    const float cnt = fmaxf(cnts[gi], 1.0f);
    g[t] = sums[(size_t)gi*HID + t] / cnt;
    __syncthreads();
    float acc = rb1[t];
    for (int k=0;k<HID;k++) acc = fmaf(g[k], rw1[(size_t)k*HID + t], acc);
    h[t] = softplusf(acc);
    __syncthreads();
    if (t < HID/2){
        float a2 = rb2[t];
        for (int k=0;k<HID;k++) a2 = fmaf(h[k], rw2[(size_t)k*(HID/2) + t], a2);
        h2[t] = softplusf(a2);
    }
    __syncthreads();
    red[t] = (t < HID/2) ? h2[t]*rw3[t] : 0.0f;
    __syncthreads();
    for (int s2=128; s2>0; s2>>=1){
        if (t < s2) red[t] += red[t+s2];
        __syncthreads();
    }
    if (t == 0) out[gi] = red[0] + rb3[0];
}

// ---------------------------------------------------------------- launcher
extern "C" void kernel_launch(void* const* d_in, const int* in_sizes, int n_in,
                              void* d_out, int out_size, void* d_ws, size_t ws_size,
                              hipStream_t stream)
{
    const int*   x_atoms = (const int*)d_in[0];
    const int*   eidx    = (const int*)d_in[1];
    const int*   src     = eidx;               // edge_index[0]
    const int*   dst     = eidx + N_EDGES;     // edge_index[1]
    const float* ea      = (const float*)d_in[2];
    const int*   batch   = (const int*)d_in[3];
    const float* emb     = (const float*)d_in[4];
    const float* ew1_0   = (const float*)d_in[5];
    const float* eb1_0   = (const float*)d_in[6];
    const float* ew2_0   = (const float*)d_in[7];
    const float* eb2_0   = (const float*)d_in[8];
    const float* nw_0    = (const float*)d_in[9];
    const float* nb_0    = (const float*)d_in[10];
    const float* ew1     = (const float*)d_in[11];
    const float* eb1     = (const float*)d_in[12];
    const float* ew2     = (const float*)d_in[13];
    const float* eb2     = (const float*)d_in[14];
    const float* nw      = (const float*)d_in[15];
    const float* nb      = (const float*)d_in[16];
    const float* rw1     = (const float*)d_in[17];
    const float* rb1     = (const float*)d_in[18];
    const float* rw2     = (const float*)d_in[19];
    const float* rb2     = (const float*)d_in[20];
    const float* rw3     = (const float*)d_in[21];
    const float* rb3     = (const float*)d_in[22];
    float* out = (float*)d_out;

    float* x    = (float*)d_ws;
    float* agg  = x   + (size_t)N_NODES*HID;
    float* sums = agg + (size_t)N_NODES*HID;
    float* cnts = sums + (size_t)N_GRAPHS*HID;
    unsigned short* whi  = (unsigned short*)(cnts + N_GRAPHS);
    unsigned short* wlo  = whi  + (size_t)3*128*512;
    unsigned short* nwhi = wlo  + (size_t)3*128*512;
    unsigned short* nwlo = nwhi + (size_t)3*128*512;
    int* hist   = (int*)(nwlo + (size_t)3*128*512);
    int* cursor = hist   + N_NODES;
    int* perm_s = cursor + N_NODES;
    int* src_s  = perm_s + N_EDGES;
    int* dst_s  = src_s  + N_EDGES;

    // ---- counting sort of edges by dst (once per launch) ----
    hipMemsetAsync(hist, 0, N_NODES*sizeof(int), stream);
    hipLaunchKernelGGL(hist_kernel, dim3((N_EDGES+255)/256), dim3(256), 0, stream, dst, hist);
    hipLaunchKernelGGL(scan_kernel, dim3(1), dim3(1024), 0, stream, hist, cursor);
    hipLaunchKernelGGL(scatter_kernel, dim3((N_EDGES+255)/256), dim3(256), 0, stream,
                       src, dst, cursor, perm_s, src_s, dst_s);

    // ---- pack weights for MFMA ----
    hipLaunchKernelGGL(pack_w_kernel, dim3(384), dim3(256), 0, stream, ew2, whi, wlo);
    hipLaunchKernelGGL(pack_w_kernel, dim3(384), dim3(256), 0, stream, nw, nwhi, nwlo);

    // ---- layer 0 (C = 92) ----
    hipLaunchKernelGGL(gather_emb_kernel, dim3(N_NODES), dim3(128), 0, stream, x_atoms, emb, x);
    hipMemsetAsync(agg, 0, (size_t)N_NODES*EMB_DIM*sizeof(float), stream);
    hipLaunchKernelGGL(edge_conv92_kernel, dim3(N_EDGES/16), dim3(128), 0, stream,
                       perm_s, src_s, dst_s, ea, ew1_0, eb1_0, ew2_0, eb2_0, x, agg);
    hipLaunchKernelGGL(node_update92_kernel, dim3(N_NODES/4), dim3(256), 0, stream,
                       agg, nw_0, nb_0, x);

    // ---- layers 1..3 (C = 256), MFMA ----
    for (int i=0;i<3;i++){
        hipMemsetAsync(agg, 0, (size_t)N_NODES*HID*sizeof(float), stream);
        hipLaunchKernelGGL(edge_conv256_mfma_kernel, dim3(N_EDGES/32), dim3(256), 0, stream,
                           perm_s, src_s, dst_s, ea,
                           ew1 + (size_t)i*4*HID, eb1 + (size_t)i*HID,
                           whi + (size_t)i*128*512, wlo + (size_t)i*128*512,
                           eb2 + (size_t)i*HID,
                           x, agg);
        hipLaunchKernelGGL(node_update_mfma_kernel, dim3((N_NODES+15)/16), dim3(256), 0, stream,
                           agg, nwhi + (size_t)i*128*512, nwlo + (size_t)i*128*512,
                           nb + (size_t)i*HID, x);
    }

    // ---- pool + readout ----
    hipMemsetAsync(sums, 0, ((size_t)N_GRAPHS*HID + N_GRAPHS)*sizeof(float), stream);
    hipLaunchKernelGGL(pool_kernel, dim3((N_NODES+31)/32), dim3(256), 0, stream, x, batch, sums, cnts);
    hipLaunchKernelGGL(readout_kernel, dim3(N_GRAPHS), dim3(256), 0, stream,
                       sums, cnts, rw1, rb1, rw2, rb2, rw3, rb3, out);
}